// Round 12
// baseline (213.857 us; speedup 1.0000x reference)
//
#include <hip/hip_runtime.h>
#include <math.h>

#define N_NODES 50000
#define N_EDGES 800000
#define HID 128
#define HEADS 8
#define HDIM 16
#define NBIN 196           // ceil(N_NODES / 256) coarse bins (dst>>8)
#define CAPB 5120          // records per bin region; lambda=4096, +16 sigma
#define K2_BLOCKS 196      // binning blocks, 4096 edges each (196*4096 >= 800000)
#define QKV_BLOCKS 782     // ceil(N_NODES / 64)
#define NFB_BLOCKS 3125    // N_NODES*HID / (256*8)

typedef __attribute__((ext_vector_type(8))) short short8;
typedef __attribute__((ext_vector_type(4))) float floatx4;

#if defined(__has_builtin)
#if __has_builtin(__builtin_amdgcn_fdot2_f32_bf16)
#define HAVE_DOT2 1
#endif
#endif
#ifndef HAVE_DOT2
#define HAVE_DOT2 0
#endif

#if HAVE_DOT2
typedef __attribute__((ext_vector_type(2))) __bf16 bf16x2;
__device__ __forceinline__ float dot2acc(unsigned int a, unsigned int b, float c) {
    return __builtin_amdgcn_fdot2_f32_bf16(__builtin_bit_cast(bf16x2, a),
                                           __builtin_bit_cast(bf16x2, b), c, false);
}
#endif

__device__ __forceinline__ float bf_lo(unsigned int d) { return __uint_as_float(d << 16); }
__device__ __forceinline__ float bf_hi(unsigned int d) { return __uint_as_float(d & 0xFFFF0000u); }
__device__ __forceinline__ unsigned short f2bf(float f) {
    unsigned int u = __float_as_uint(f);
    u = (u + 0x7FFFu + ((u >> 16) & 1u)) >> 16;  // RNE
    return (unsigned short)u;
}
__device__ __forceinline__ unsigned int pack_bf2(float a, float b) {
    return (unsigned int)f2bf(a) | ((unsigned int)f2bf(b) << 16);
}

// ---- fused prep: edge coarse-binning (K2, two-pass streaming, no per-thread arrays)
//      | nf->bf16 | W->bf16^T | rel->bf16 | bias folds ----
__global__ __launch_bounds__(256) void prep_kernel(
    const float* __restrict__ nf,
    const float* __restrict__ query, const float* __restrict__ rel,
    const float* __restrict__ Wq, const float* __restrict__ bq,
    const float* __restrict__ Wk, const float* __restrict__ bk,
    const float* __restrict__ Wv, const float* __restrict__ Wo,
    const int* __restrict__ ei, const int* __restrict__ et,
    int* __restrict__ cursor, unsigned long long* __restrict__ recs,
    unsigned short* __restrict__ Wt, unsigned short* __restrict__ relbf,
    float* __restrict__ bqe, float* __restrict__ bke,
    unsigned short* __restrict__ nfb) {
    int b = blockIdx.x, tid = threadIdx.x;
    if (b < K2_BLOCKS) {
        __shared__ int hist[NBIN];
        __shared__ int base2[NBIN];
        __shared__ int lcur[NBIN];
        for (int i = tid; i < NBIN; i += 256) { hist[i] = 0; lcur[i] = 0; }
        __syncthreads();
        int e0 = b * 4096;
        // pass 1: histogram of dst>>8 (stream, no state kept)
        for (int i = 0; i < 16; ++i) {
            int e = e0 + i * 256 + tid;
            if (e < N_EDGES)
                atomicAdd(&hist[((unsigned)ei[N_EDGES + e]) >> 8], 1);
        }
        __syncthreads();
        for (int i = tid; i < NBIN; i += 256) {
            int c = hist[i];
            base2[i] = (c > 0) ? (i * CAPB + atomicAdd(&cursor[i], c)) : 0;
        }
        __syncthreads();
        // pass 2: re-read edges (L2-hot) and write records densely per bin
        for (int i = 0; i < 16; ++i) {
            int e = e0 + i * 256 + tid;
            if (e < N_EDGES) {
                unsigned int d = (unsigned)ei[N_EDGES + e];
                unsigned int s = (unsigned)ei[e];
                unsigned int t = (unsigned)et[e];
                int bin = (int)(d >> 8);
                int pos = atomicAdd(&lcur[bin], 1);
                recs[(size_t)base2[bin] + pos] =
                    ((unsigned long long)d << 22) | (t << 16) | s;
            }
        }
        return;
    }
    b -= K2_BLOCKS;
    if (b < NFB_BLOCKS) {
        // nf -> bf16, 8 elems/thread
        int base = b * 2048 + tid * 8;   // < 6,400,000 exactly
        const float4* p = (const float4*)(nf + base);
        float4 a0 = p[0], a1 = p[1];
        short8 f;
        f[0] = (short)f2bf(a0.x); f[1] = (short)f2bf(a0.y);
        f[2] = (short)f2bf(a0.z); f[3] = (short)f2bf(a0.w);
        f[4] = (short)f2bf(a1.x); f[5] = (short)f2bf(a1.y);
        f[6] = (short)f2bf(a1.z); f[7] = (short)f2bf(a1.w);
        *(short8*)(nfb + base) = f;
        return;
    }
    b -= NFB_BLOCKS;
    if (b < 256) {
        int idx = b * 256 + tid;  // < 65536
        if (idx < 64 * HID) relbf[idx] = f2bf(rel[idx]);
        int m = idx >> 14;
        int rem = idx & 16383;
        int n = rem >> 7, k = rem & 127;
        const float* W = (m == 0) ? Wq : (m == 1) ? Wk : (m == 2) ? Wv : Wo;
        Wt[idx] = f2bf(W[k * HID + n]);  // Wq/Wk: rows 0..127 only (query part folded into bias)
        return;
    }
    // b==256: fold query@Wq[128:] + bq -> bqe ; b==257: same for k
    {
        __shared__ float fred[256];
        const float* W  = (b == 256) ? Wq : Wk;
        const float* bb = (b == 256) ? bq : bk;
        float* dst      = (b == 256) ? bqe : bke;
        int j = tid & 127;
        int half = tid >> 7;
        float a = 0.0f;
        int i0 = half * 64;
        for (int i = 0; i < 64; ++i) a += query[i0 + i] * W[(HID + i0 + i) * HID + j];
        fred[tid] = a;
        __syncthreads();
        if (half == 0) dst[j] = fred[j] + fred[128 + j] + bb[j];
    }
}

// ---- fused: per-bucket counting sort (K3, blocks [0,NBIN)) | monolithic QKV MFMA + LDS epilogue ----
__global__ __launch_bounds__(256) void qkv_kernel(
    const unsigned short* __restrict__ nfb, const unsigned short* __restrict__ Wt,
    const float* __restrict__ bqe, const float* __restrict__ bke, const float* __restrict__ bv,
    const int* __restrict__ cursor, const unsigned long long* __restrict__ recs,
    unsigned int* __restrict__ esort, unsigned int* __restrict__ nodeinfo,
    unsigned short* __restrict__ qb16, unsigned short* __restrict__ kv16) {
    if (blockIdx.x < NBIN) {
        int bkt = blockIdx.x;
        int tid = threadIdx.x;
        __shared__ int hist[256];
        __shared__ int scan[256];
        __shared__ int sbase[256];
        __shared__ int lcur[256];
        hist[tid] = 0; lcur[tid] = 0;
        __syncthreads();
        int cnt = cursor[bkt];
        const unsigned long long* rb = recs + (size_t)bkt * CAPB;
        for (int i = tid; i < cnt; i += 256)
            atomicAdd(&hist[(int)((rb[i] >> 22) & 0xFF)], 1);
        __syncthreads();
        int v = hist[tid];
        scan[tid] = v;
        __syncthreads();
        for (int off = 1; off < 256; off <<= 1) {
            int a = (tid >= off) ? scan[tid - off] : 0;
            __syncthreads();
            scan[tid] += a;
            __syncthreads();
        }
        int excl = scan[tid] - v;
        sbase[tid] = excl;
        int node = bkt * 256 + tid;
        if (node < N_NODES) {
            unsigned int startg = (unsigned)(bkt * CAPB + excl);
            unsigned int deg = (unsigned)(v < 255 ? v : 255);
            nodeinfo[node] = (startg << 8) | deg;
        }
        __syncthreads();
        for (int i = tid; i < cnt; i += 256) {
            unsigned long long r = rb[i];
            int low = (int)((r >> 22) & 0xFF);
            int pos = atomicAdd(&lcur[low], 1);
            esort[(size_t)bkt * CAPB + sbase[low] + pos] = (unsigned int)(r & 0x3FFFFF);
        }
        return;
    }
    int row0 = (blockIdx.x - NBIN) * 64;
    int wave = threadIdx.x >> 6;   // n-range selector
    int lane = threadIdx.x & 63;
    int col  = lane & 15;
    int quad = lane >> 4;
    __shared__ unsigned short ctile[64][136];  // bf16 C tile, padded (16B-aligned rows)

    short8 afr[4][4];
    #pragma unroll
    for (int t = 0; t < 4; ++t) {
        int arow = row0 + t * 16 + col;
        int asafe = (arow < N_NODES) ? arow : (N_NODES - 1);
        #pragma unroll
        for (int kk = 0; kk < 4; ++kk)
            afr[t][kk] = *(const short8*)(nfb + (size_t)asafe * HID + kk * 32 + quad * 8);
    }
    const float* biases[3] = {bqe, bke, bv};
    #pragma unroll
    for (int m = 0; m < 3; ++m) {
        const unsigned short* W = Wt + (size_t)m * HID * HID;
        #pragma unroll
        for (int nn = 0; nn < 2; ++nn) {
            int n = wave * 2 + nn;
            float b = biases[m][n * 16 + col];
            floatx4 acc[4];
            #pragma unroll
            for (int t = 0; t < 4; ++t) acc[t] = (floatx4){b, b, b, b};
            short8 bfr[4];
            #pragma unroll
            for (int kk = 0; kk < 4; ++kk)
                bfr[kk] = *(const short8*)(W + (size_t)(n * 16 + col) * HID + kk * 32 + quad * 8);
            #pragma unroll
            for (int kk = 0; kk < 4; ++kk)
                #pragma unroll
                for (int t = 0; t < 4; ++t)
                    acc[t] = __builtin_amdgcn_mfma_f32_16x16x32_bf16(afr[t][kk], bfr[kk], acc[t], 0, 0, 0);
            #pragma unroll
            for (int t = 0; t < 4; ++t)
                #pragma unroll
                for (int i = 0; i < 4; ++i)
                    ctile[t * 16 + quad * 4 + i][n * 16 + col] = f2bf(acc[t][i]);
        }
        __syncthreads();
        // coalesced copy-out: 1024 chunks of 16B, 4 per thread
        #pragma unroll
        for (int k = 0; k < 4; ++k) {
            int chunk = threadIdx.x + k * 256;
            int r = chunk >> 4, c = chunk & 15;
            int row = row0 + r;
            if (row < N_NODES) {
                uint4 v = *(const uint4*)&ctile[r][c * 8];
                unsigned short* dst = (m == 0) ? (qb16 + (size_t)row * HID + c * 8)
                                               : (kv16 + (size_t)row * 256 + (m == 2 ? 128 : 0) + c * 8);
                *(uint4*)dst = v;
            }
        }
        __syncthreads();
    }
}

// ---- attention: 1 wave/node; 16 edges/iter, straight-line branch-free (R9-verbatim) ----
__global__ __launch_bounds__(256) void attn_kernel(
    const unsigned int* __restrict__ qb, const unsigned int* __restrict__ kvu,
    const unsigned int* __restrict__ relu,
    const unsigned int* __restrict__ nodeinfo, const unsigned int* __restrict__ esort,
    unsigned int* __restrict__ abuf) {
    int node = blockIdx.x * 4 + (threadIdx.x >> 6);
    int lane = threadIdx.x & 63;
    int h = lane & 7;        // head, score phase
    int hd = lane >> 3;      // edge sub-slot, score phase (owns edges base+hd and base+hd+8)
    int qi = lane & 15;      // V-row element group, PV phase: uints [4qi..4qi+3], head qi>>1
    int quarter = lane >> 4; // edge sub-slot, PV phase
    unsigned int info = nodeinfo[node];
    int deg = (int)(info & 0xFF);
    unsigned int start = info >> 8;

    const uint4* qp = (const uint4*)(qb + (unsigned)node * 64 + h * 8);
    uint4 qa = qp[0], qc = qp[1];
#if !HAVE_DOT2
    float qf0 = bf_lo(qa.x), qf1 = bf_hi(qa.x), qf2 = bf_lo(qa.y), qf3 = bf_hi(qa.y);
    float qf4 = bf_lo(qa.z), qf5 = bf_hi(qa.z), qf6 = bf_lo(qa.w), qf7 = bf_hi(qa.w);
    float qf8 = bf_lo(qc.x), qf9 = bf_hi(qc.x), qf10 = bf_lo(qc.y), qf11 = bf_hi(qc.y);
    float qf12 = bf_lo(qc.z), qf13 = bf_hi(qc.z), qf14 = bf_lo(qc.w), qf15 = bf_hi(qc.w);
#endif

    float ssum = 0.0f;
    float acc[8] = {0.f, 0.f, 0.f, 0.f, 0.f, 0.f, 0.f, 0.f};
    for (int base = 0; base < deg; base += 16) {
        int el0 = base + hd;
        int el1 = el0 + 8;
        unsigned int pk0 = esort[start + ((el0 < deg) ? el0 : 0)];
        unsigned int pk1 = esort[start + ((el1 < deg) ? el1 : 0)];
        unsigned int src0 = pk0 & 0xFFFF, etv0 = (pk0 >> 16) & 0x3F;
        unsigned int src1 = pk1 & 0xFFFF, etv1 = (pk1 >> 16) & 0x3F;
        const uint4* kp0 = (const uint4*)(kvu + (src0 << 7) + h * 8);
        const uint4* rp0 = (const uint4*)(relu + (etv0 << 6) + h * 8);
        const uint4* kp1 = (const uint4*)(kvu + (src1 << 7) + h * 8);
        const uint4* rp1 = (const uint4*)(relu + (etv1 << 6) + h * 8);
        uint4 ka0 = kp0[0], kb0 = kp0[1];
        uint4 ra0 = rp0[0], rb0 = rp0[1];
        uint4 ka1 = kp1[0], kb1 = kp1[1];
        uint4 ra1 = rp1[0], rb1 = rp1[1];
        float s0, s1;
#if HAVE_DOT2
        {
            float a0 = dot2acc(qa.x, ka0.x, 0.0f), a1 = dot2acc(qa.y, ka0.y, 0.0f);
            float a2 = dot2acc(qa.z, ka0.z, 0.0f), a3 = dot2acc(qa.w, ka0.w, 0.0f);
            a0 = dot2acc(qc.x, kb0.x, a0); a1 = dot2acc(qc.y, kb0.y, a1);
            a2 = dot2acc(qc.z, kb0.z, a2); a3 = dot2acc(qc.w, kb0.w, a3);
            a0 = dot2acc(qa.x, ra0.x, a0); a1 = dot2acc(qa.y, ra0.y, a1);
            a2 = dot2acc(qa.z, ra0.z, a2); a3 = dot2acc(qa.w, ra0.w, a3);
            a0 = dot2acc(qc.x, rb0.x, a0); a1 = dot2acc(qc.y, rb0.y, a1);
            a2 = dot2acc(qc.z, rb0.z, a2); a3 = dot2acc(qc.w, rb0.w, a3);
            s0 = (a0 + a1) + (a2 + a3);
        }
        {
            float a0 = dot2acc(qa.x, ka1.x, 0.0f), a1 = dot2acc(qa.y, ka1.y, 0.0f);
            float a2 = dot2acc(qa.z, ka1.z, 0.0f), a3 = dot2acc(qa.w, ka1.w, 0.0f);
            a0 = dot2acc(qc.x, kb1.x, a0); a1 = dot2acc(qc.y, kb1.y, a1);
            a2 = dot2acc(qc.z, kb1.z, a2); a3 = dot2acc(qc.w, kb1.w, a3);
            a0 = dot2acc(qa.x, ra1.x, a0); a1 = dot2acc(qa.y, ra1.y, a1);
            a2 = dot2acc(qa.z, ra1.z, a2); a3 = dot2acc(qa.w, ra1.w, a3);
            a0 = dot2acc(qc.x, rb1.x, a0); a1 = dot2acc(qc.y, rb1.y, a1);
            a2 = dot2acc(qc.z, rb1.z, a2); a3 = dot2acc(qc.w, rb1.w, a3);
            s1 = (a0 + a1) + (a2 + a3);
        }
#else
        {
            float a0 = qf0 * (bf_lo(ka0.x) + bf_lo(ra0.x)) + qf4 * (bf_lo(ka0.z) + bf_lo(ra0.z))
                     + qf8 * (bf_lo(kb0.x) + bf_lo(rb0.x)) + qf12 * (bf_lo(kb0.z) + bf_lo(rb0.z));
            float a1 = qf1 * (bf_hi(ka0.x) + bf_hi(ra0.x)) + qf5 * (bf_hi(ka0.z) + bf_hi(ra0.z))
                     + qf9 * (bf_hi(kb0.x) + bf_hi(rb0.x)) + qf13 * (bf_hi(kb0.z) + bf_hi(rb0.z));
            float a2 = qf2 * (bf_lo(ka0.y) + bf_lo(ra0.y)) + qf6 * (bf_lo(ka0.w) + bf_lo(ra0.w))
                     + qf10 * (bf_lo(kb0.y) + bf_lo(rb0.y)) + qf14 * (bf_lo(kb0.w) + bf_lo(rb0.w));
            float a3 = qf3 * (bf_hi(ka0.y) + bf_hi(ra0.y)) + qf7 * (bf_hi(ka0.w) + bf_hi(ra0.w))
                     + qf11 * (bf_hi(kb0.y) + bf_hi(rb0.y)) + qf15 * (bf_hi(kb0.w) + bf_hi(rb0.w));
            s0 = (a0 + a1) + (a2 + a3);
        }
        {
            float a0 = qf0 * (bf_lo(ka1.x) + bf_lo(ra1.x)) + qf4 * (bf_lo(ka1.z) + bf_lo(ra1.z))
                     + qf8 * (bf_lo(kb1.x) + bf_lo(rb1.x)) + qf12 * (bf_lo(kb1.z) + bf_lo(rb1.z));
            float a1 = qf1 * (bf_hi(ka1.x) + bf_hi(ra1.x)) + qf5 * (bf_hi(ka1.z) + bf_hi(ra1.z))
                     + qf9 * (bf_hi(kb1.x) + bf_hi(rb1.x)) + qf13 * (bf_hi(kb1.z) + bf_hi(rb1.z));
            float a2 = qf2 * (bf_lo(ka1.y) + bf_lo(ra1.y)) + qf6 * (bf_lo(ka1.w) + bf_lo(ra1.w))
                     + qf10 * (bf_lo(kb1.y) + bf_lo(rb1.y)) + qf14 * (bf_lo(kb1.w) + bf_lo(rb1.w));
            float a3 = qf3 * (bf_hi(ka1.y) + bf_hi(ra1.y)) + qf7 * (bf_hi(ka1.w) + bf_hi(ra1.w))
                     + qf11 * (bf_hi(kb1.y) + bf_hi(rb1.y)) + qf15 * (bf_hi(kb1.w) + bf_hi(rb1.w));
            s1 = (a0 + a1) + (a2 + a3);
        }
#endif
        unsigned int wb0 = (el0 < deg) ? (unsigned int)f2bf(__expf(s0 * 0.25f)) : 0u;
        unsigned int wb1 = (el1 < deg) ? (unsigned int)f2bf(__expf(s1 * 0.25f)) : 0u;
        ssum += __uint_as_float(wb0 << 16) + __uint_as_float(wb1 << 16);
        unsigned int pw0 = (wb0 << 16) | src0;
        unsigned int pw1 = (wb1 << 16) | src1;
        #pragma unroll
        for (int t = 0; t < 4; ++t) {
            unsigned int pj = (t < 2) ? __shfl(pw0, (t * 4 + quarter) * 8 + (qi >> 1))
                                      : __shfl(pw1, ((t - 2) * 4 + quarter) * 8 + (qi >> 1));
            float wj = bf_hi(pj);
            unsigned int sj = pj & 0xFFFFu;
            uint4 v = *(const uint4*)(kvu + (sj << 7) + 64 + qi * 4);
            acc[0] += wj * bf_lo(v.x); acc[1] += wj * bf_hi(v.x);
            acc[2] += wj * bf_lo(v.y); acc[3] += wj * bf_hi(v.y);
            acc[4] += wj * bf_lo(v.z); acc[5] += wj * bf_hi(v.z);
            acc[6] += wj * bf_lo(v.w); acc[7] += wj * bf_hi(v.w);
        }
    }
    #pragma unroll
    for (int off = 8; off < 64; off <<= 1) ssum += __shfl_xor(ssum, off);
    #pragma unroll
    for (int k = 0; k < 8; ++k) {
        acc[k] += __shfl_xor(acc[k], 16);
        acc[k] += __shfl_xor(acc[k], 32);
    }
    float inv = 1.0f / (__shfl(ssum, qi >> 1) + 1e-8f);
    if (lane < 16) {
        uint4 o;
        o.x = pack_bf2(acc[0] * inv, acc[1] * inv);
        o.y = pack_bf2(acc[2] * inv, acc[3] * inv);
        o.z = pack_bf2(acc[4] * inv, acc[5] * inv);
        o.w = pack_bf2(acc[6] * inv, acc[7] * inv);
        *(uint4*)(abuf + (unsigned)node * 64 + qi * 4) = o;
    }
}

// ---- out = Abf16 @ Wo + bo via MFMA; fp32 LDS-staged epilogue for full-sector streaming stores ----
__global__ __launch_bounds__(256) void out_mfma_kernel(
    const unsigned short* __restrict__ abuf, const unsigned short* __restrict__ Wot,
    const float* __restrict__ bo, float* __restrict__ out) {
    int row0 = blockIdx.x * 64;
    int wave = threadIdx.x >> 6;
    int lane = threadIdx.x & 63;
    int col  = lane & 15;
    int quad = lane >> 4;
    __shared__ float otile[64][132];   // fp32 C tile, 528B rows (16B-aligned)

    short8 afr[4][4];
    #pragma unroll
    for (int t = 0; t < 4; ++t) {
        int arow = row0 + t * 16 + col;
        int asafe = (arow < N_NODES) ? arow : (N_NODES - 1);
        #pragma unroll
        for (int kk = 0; kk < 4; ++kk)
            afr[t][kk] = *(const short8*)(abuf + (size_t)asafe * HID + kk * 32 + quad * 8);
    }

    #pragma unroll
    for (int nn = 0; nn < 2; ++nn) {
        int n = wave * 2 + nn;
        float b = bo[n * 16 + col];
        floatx4 acc[4];
        #pragma unroll
        for (int t = 0; t < 4; ++t) acc[t] = (floatx4){b, b, b, b};
        short8 bfr[4];
        #pragma unroll
        for (int kk = 0; kk < 4; ++kk)
            bfr[kk] = *(const short8*)(Wot + (size_t)(n * 16 + col) * HID + kk * 32 + quad * 8);
        #pragma unroll
        for (int kk = 0; kk < 4; ++kk)
            #pragma unroll
            for (int t = 0; t < 4; ++t)
                acc[t] = __builtin_amdgcn_mfma_f32_16x16x32_bf16(afr[t][kk], bfr[kk], acc[t], 0, 0, 0);
        #pragma unroll
        for (int t = 0; t < 4; ++t)
            #pragma unroll
            for (int i = 0; i < 4; ++i)
                otile[t * 16 + quad * 4 + i][n * 16 + col] = acc[t][i];
    }
    __syncthreads();
    // coalesced copy-out: 2048 chunks of 16B (64 rows x 512B), 8 per thread
    #pragma unroll
    for (int k = 0; k < 8; ++k) {
        int chunk = threadIdx.x + k * 256;
        int r = chunk >> 5, c = chunk & 31;
        int row = row0 + r;
        if (row < N_NODES) {
            float4 v = *(const float4*)&otile[r][c * 4];
            *(float4*)(out + (size_t)row * HID + c * 4) = v;
        }
    }
}

extern "C" void kernel_launch(void* const* d_in, const int* in_sizes, int n_in,
                              void* d_out, int out_size, void* d_ws, size_t ws_size,
                              hipStream_t stream) {
    const float* nf    = (const float*)d_in[0];
    const float* query = (const float*)d_in[1];
    const float* rel   = (const float*)d_in[2];
    const float* Wq    = (const float*)d_in[3];
    const float* bq    = (const float*)d_in[4];
    const float* Wk    = (const float*)d_in[5];
    const float* bk    = (const float*)d_in[6];
    const float* Wv    = (const float*)d_in[7];
    const float* bv    = (const float*)d_in[8];
    const float* Wo    = (const float*)d_in[9];
    const float* bo    = (const float*)d_in[10];
    const int*   ei    = (const int*)d_in[11];
    const int*   et    = (const int*)d_in[12];
    float* out = (float*)d_out;

    char* ws = (char*)d_ws;
    unsigned short* qb16 = (unsigned short*)ws; ws += (size_t)N_NODES * HID * 2;
    unsigned short* kv16 = (unsigned short*)ws; ws += (size_t)N_NODES * 256 * 2;
    unsigned int* abuf   = (unsigned int*)ws;   ws += (size_t)N_NODES * 64 * 4;
    float* bqe           = (float*)ws;          ws += 128 * 4;
    float* bke           = (float*)ws;          ws += 128 * 4;
    unsigned short* Wt   = (unsigned short*)ws; ws += (size_t)4 * HID * HID * 2;
    unsigned short* relbf = (unsigned short*)ws; ws += (size_t)64 * HID * 2;
    unsigned short* nfb  = (unsigned short*)ws; ws += (size_t)N_NODES * HID * 2;
    unsigned long long* recs = (unsigned long long*)ws; ws += (size_t)NBIN * CAPB * 8;
    unsigned int* esort  = (unsigned int*)ws;   ws += (size_t)NBIN * CAPB * 4;
    unsigned int* nodeinfo = (unsigned int*)ws; ws += (size_t)N_NODES * 4;
    int* cursor          = (int*)ws;            ws += (size_t)NBIN * 4;

    hipMemsetAsync(cursor, 0, (size_t)NBIN * 4, stream);
    prep_kernel<<<K2_BLOCKS + NFB_BLOCKS + 258, 256, 0, stream>>>(
        nf, query, rel, Wq, bq, Wk, bk, Wv, Wo, ei, et,
        cursor, recs, Wt, relbf, bqe, bke, nfb);
    qkv_kernel<<<NBIN + QKV_BLOCKS, 256, 0, stream>>>(
        nfb, Wt, bqe, bke, bv, cursor, recs, esort, nodeinfo, qb16, kv16);
    attn_kernel<<<N_NODES / 4, 256, 0, stream>>>(
        (const unsigned int*)qb16, (const unsigned int*)kv16,
        (const unsigned int*)relbf, nodeinfo, esort, abuf);
    out_mfma_kernel<<<QKV_BLOCKS, 256, 0, stream>>>(
        (const unsigned short*)abuf, Wt + (size_t)3 * HID * HID, bo, out);
}

// Round 13
// 207.161 us; speedup vs baseline: 1.0323x; 1.0323x over previous
//
#include <hip/hip_runtime.h>
#include <math.h>

#define N_NODES 50000
#define N_EDGES 800000
#define HID 128
#define HEADS 8
#define HDIM 16
#define NBIN 196           // ceil(N_NODES / 256) coarse bins (dst>>8)
#define CAPB 5120          // records per bin region; lambda=4096, +16 sigma
#define K2_BLOCKS 196      // binning blocks, 4096 edges each (196*4096 >= 800000)
#define K2_EPT 16          // edges per thread in binning
#define QKV_BLOCKS 782     // ceil(N_NODES / 64)
#define NFB_BLOCKS 3125    // N_NODES*HID / (256*8)

typedef __attribute__((ext_vector_type(8))) short short8;
typedef __attribute__((ext_vector_type(4))) float floatx4;

#if defined(__has_builtin)
#if __has_builtin(__builtin_amdgcn_fdot2_f32_bf16)
#define HAVE_DOT2 1
#endif
#endif
#ifndef HAVE_DOT2
#define HAVE_DOT2 0
#endif

#if HAVE_DOT2
typedef __attribute__((ext_vector_type(2))) __bf16 bf16x2;
__device__ __forceinline__ float dot2acc(unsigned int a, unsigned int b, float c) {
    return __builtin_amdgcn_fdot2_f32_bf16(__builtin_bit_cast(bf16x2, a),
                                           __builtin_bit_cast(bf16x2, b), c, false);
}
#endif

__device__ __forceinline__ float bf_lo(unsigned int d) { return __uint_as_float(d << 16); }
__device__ __forceinline__ float bf_hi(unsigned int d) { return __uint_as_float(d & 0xFFFF0000u); }
__device__ __forceinline__ unsigned short f2bf(float f) {
    unsigned int u = __float_as_uint(f);
    u = (u + 0x7FFFu + ((u >> 16) & 1u)) >> 16;  // RNE
    return (unsigned short)u;
}
__device__ __forceinline__ unsigned int pack_bf2(float a, float b) {
    return (unsigned int)f2bf(a) | ((unsigned int)f2bf(b) << 16);
}

// ---- fused prep: edge coarse-binning (K2, 4B records) | nf->bf16 | W->bf16^T | rel->bf16 | bias folds ----
// record = (dst&0xFF)<<22 | et<<16 | src : K3 only needs dst's low byte (bucket supplies high bits)
__global__ __launch_bounds__(256) void prep_kernel(
    const float* __restrict__ nf,
    const float* __restrict__ query, const float* __restrict__ rel,
    const float* __restrict__ Wq, const float* __restrict__ bq,
    const float* __restrict__ Wk, const float* __restrict__ bk,
    const float* __restrict__ Wv, const float* __restrict__ Wo,
    const int* __restrict__ ei, const int* __restrict__ et,
    int* __restrict__ cursor, unsigned int* __restrict__ recs,
    unsigned short* __restrict__ Wt, unsigned short* __restrict__ relbf,
    float* __restrict__ bqe, float* __restrict__ bke,
    unsigned short* __restrict__ nfb) {
    int b = blockIdx.x, tid = threadIdx.x;
    if (b < K2_BLOCKS) {
        __shared__ int hist[NBIN];
        __shared__ int base2[NBIN];
        __shared__ int lcur[NBIN];
        for (int i = tid; i < NBIN; i += 256) { hist[i] = 0; lcur[i] = 0; }
        __syncthreads();
        int e0 = b * (256 * K2_EPT);
        unsigned int rec[K2_EPT];
        int bin[K2_EPT];
        #pragma unroll
        for (int i = 0; i < K2_EPT; ++i) {
            int e = e0 + i * 256 + tid;
            bin[i] = -1;
            if (e < N_EDGES) {
                unsigned int d = (unsigned)ei[N_EDGES + e];
                unsigned int s = (unsigned)ei[e];
                unsigned int t = (unsigned)et[e];
                rec[i] = ((d & 0xFFu) << 22) | (t << 16) | s;
                bin[i] = (int)(d >> 8);
                atomicAdd(&hist[bin[i]], 1);
            }
        }
        __syncthreads();
        for (int i = tid; i < NBIN; i += 256) {
            int c = hist[i];
            base2[i] = (c > 0) ? (i * CAPB + atomicAdd(&cursor[i], c)) : 0;
        }
        __syncthreads();
        #pragma unroll
        for (int i = 0; i < K2_EPT; ++i) {
            if (bin[i] >= 0) {
                int pos = atomicAdd(&lcur[bin[i]], 1);
                recs[(size_t)base2[bin[i]] + pos] = rec[i];
            }
        }
        return;
    }
    b -= K2_BLOCKS;
    if (b < NFB_BLOCKS) {
        // nf -> bf16, 8 elems/thread
        int base = b * 2048 + tid * 8;   // < 6,400,000 exactly
        const float4* p = (const float4*)(nf + base);
        float4 a0 = p[0], a1 = p[1];
        short8 f;
        f[0] = (short)f2bf(a0.x); f[1] = (short)f2bf(a0.y);
        f[2] = (short)f2bf(a0.z); f[3] = (short)f2bf(a0.w);
        f[4] = (short)f2bf(a1.x); f[5] = (short)f2bf(a1.y);
        f[6] = (short)f2bf(a1.z); f[7] = (short)f2bf(a1.w);
        *(short8*)(nfb + base) = f;
        return;
    }
    b -= NFB_BLOCKS;
    if (b < 256) {
        int idx = b * 256 + tid;  // < 65536
        if (idx < 64 * HID) relbf[idx] = f2bf(rel[idx]);
        int m = idx >> 14;
        int rem = idx & 16383;
        int n = rem >> 7, k = rem & 127;
        const float* W = (m == 0) ? Wq : (m == 1) ? Wk : (m == 2) ? Wv : Wo;
        Wt[idx] = f2bf(W[k * HID + n]);  // Wq/Wk: rows 0..127 only (query part folded into bias)
        return;
    }
    // b==256: fold query@Wq[128:] + bq -> bqe ; b==257: same for k
    {
        __shared__ float fred[256];
        const float* W  = (b == 256) ? Wq : Wk;
        const float* bb = (b == 256) ? bq : bk;
        float* dst      = (b == 256) ? bqe : bke;
        int j = tid & 127;
        int half = tid >> 7;
        float a = 0.0f;
        int i0 = half * 64;
        for (int i = 0; i < 64; ++i) a += query[i0 + i] * W[(HID + i0 + i) * HID + j];
        fred[tid] = a;
        __syncthreads();
        if (half == 0) dst[j] = fred[j] + fred[128 + j] + bb[j];
    }
}

// ---- fused: per-bucket counting sort (K3, blocks [0,NBIN), 4B records) | monolithic QKV MFMA + LDS epilogue ----
__global__ __launch_bounds__(256) void qkv_kernel(
    const unsigned short* __restrict__ nfb, const unsigned short* __restrict__ Wt,
    const float* __restrict__ bqe, const float* __restrict__ bke, const float* __restrict__ bv,
    const int* __restrict__ cursor, const unsigned int* __restrict__ recs,
    unsigned int* __restrict__ esort, unsigned int* __restrict__ nodeinfo,
    unsigned short* __restrict__ qb16, unsigned short* __restrict__ kv16) {
    if (blockIdx.x < NBIN) {
        int bkt = blockIdx.x;
        int tid = threadIdx.x;
        __shared__ int hist[256];
        __shared__ int scan[256];
        __shared__ int sbase[256];
        __shared__ int lcur[256];
        hist[tid] = 0; lcur[tid] = 0;
        __syncthreads();
        int cnt = cursor[bkt];
        const unsigned int* rb = recs + (size_t)bkt * CAPB;
        for (int i = tid; i < cnt; i += 256)
            atomicAdd(&hist[(int)((rb[i] >> 22) & 0xFF)], 1);
        __syncthreads();
        int v = hist[tid];
        scan[tid] = v;
        __syncthreads();
        for (int off = 1; off < 256; off <<= 1) {
            int a = (tid >= off) ? scan[tid - off] : 0;
            __syncthreads();
            scan[tid] += a;
            __syncthreads();
        }
        int excl = scan[tid] - v;
        sbase[tid] = excl;
        int node = bkt * 256 + tid;
        if (node < N_NODES) {
            unsigned int startg = (unsigned)(bkt * CAPB + excl);
            unsigned int deg = (unsigned)(v < 255 ? v : 255);
            nodeinfo[node] = (startg << 8) | deg;
        }
        __syncthreads();
        for (int i = tid; i < cnt; i += 256) {
            unsigned int r = rb[i];
            int low = (int)((r >> 22) & 0xFF);
            int pos = atomicAdd(&lcur[low], 1);
            esort[(size_t)bkt * CAPB + sbase[low] + pos] = r & 0x3FFFFF;
        }
        return;
    }
    int row0 = (blockIdx.x - NBIN) * 64;
    int wave = threadIdx.x >> 6;   // n-range selector
    int lane = threadIdx.x & 63;
    int col  = lane & 15;
    int quad = lane >> 4;
    __shared__ unsigned short ctile[64][136];  // bf16 C tile, padded (16B-aligned rows)

    short8 afr[4][4];
    #pragma unroll
    for (int t = 0; t < 4; ++t) {
        int arow = row0 + t * 16 + col;
        int asafe = (arow < N_NODES) ? arow : (N_NODES - 1);
        #pragma unroll
        for (int kk = 0; kk < 4; ++kk)
            afr[t][kk] = *(const short8*)(nfb + (size_t)asafe * HID + kk * 32 + quad * 8);
    }
    const float* biases[3] = {bqe, bke, bv};
    #pragma unroll
    for (int m = 0; m < 3; ++m) {
        const unsigned short* W = Wt + (size_t)m * HID * HID;
        #pragma unroll
        for (int nn = 0; nn < 2; ++nn) {
            int n = wave * 2 + nn;
            float b = biases[m][n * 16 + col];
            floatx4 acc[4];
            #pragma unroll
            for (int t = 0; t < 4; ++t) acc[t] = (floatx4){b, b, b, b};
            short8 bfr[4];
            #pragma unroll
            for (int kk = 0; kk < 4; ++kk)
                bfr[kk] = *(const short8*)(W + (size_t)(n * 16 + col) * HID + kk * 32 + quad * 8);
            #pragma unroll
            for (int kk = 0; kk < 4; ++kk)
                #pragma unroll
                for (int t = 0; t < 4; ++t)
                    acc[t] = __builtin_amdgcn_mfma_f32_16x16x32_bf16(afr[t][kk], bfr[kk], acc[t], 0, 0, 0);
            #pragma unroll
            for (int t = 0; t < 4; ++t)
                #pragma unroll
                for (int i = 0; i < 4; ++i)
                    ctile[t * 16 + quad * 4 + i][n * 16 + col] = f2bf(acc[t][i]);
        }
        __syncthreads();
        // coalesced copy-out: 1024 chunks of 16B, 4 per thread
        #pragma unroll
        for (int k = 0; k < 4; ++k) {
            int chunk = threadIdx.x + k * 256;
            int r = chunk >> 4, c = chunk & 15;
            int row = row0 + r;
            if (row < N_NODES) {
                uint4 v = *(const uint4*)&ctile[r][c * 8];
                unsigned short* dst = (m == 0) ? (qb16 + (size_t)row * HID + c * 8)
                                               : (kv16 + (size_t)row * 256 + (m == 2 ? 128 : 0) + c * 8);
                *(uint4*)dst = v;
            }
        }
        __syncthreads();
    }
}

// ---- attention: 1 wave/node; 16 edges/iter, straight-line branch-free (R9-verbatim) ----
__global__ __launch_bounds__(256) void attn_kernel(
    const unsigned int* __restrict__ qb, const unsigned int* __restrict__ kvu,
    const unsigned int* __restrict__ relu,
    const unsigned int* __restrict__ nodeinfo, const unsigned int* __restrict__ esort,
    unsigned int* __restrict__ abuf) {
    int node = blockIdx.x * 4 + (threadIdx.x >> 6);
    int lane = threadIdx.x & 63;
    int h = lane & 7;        // head, score phase
    int hd = lane >> 3;      // edge sub-slot, score phase (owns edges base+hd and base+hd+8)
    int qi = lane & 15;      // V-row element group, PV phase: uints [4qi..4qi+3], head qi>>1
    int quarter = lane >> 4; // edge sub-slot, PV phase
    unsigned int info = nodeinfo[node];
    int deg = (int)(info & 0xFF);
    unsigned int start = info >> 8;

    const uint4* qp = (const uint4*)(qb + (unsigned)node * 64 + h * 8);
    uint4 qa = qp[0], qc = qp[1];
#if !HAVE_DOT2
    float qf0 = bf_lo(qa.x), qf1 = bf_hi(qa.x), qf2 = bf_lo(qa.y), qf3 = bf_hi(qa.y);
    float qf4 = bf_lo(qa.z), qf5 = bf_hi(qa.z), qf6 = bf_lo(qa.w), qf7 = bf_hi(qa.w);
    float qf8 = bf_lo(qc.x), qf9 = bf_hi(qc.x), qf10 = bf_lo(qc.y), qf11 = bf_hi(qc.y);
    float qf12 = bf_lo(qc.z), qf13 = bf_hi(qc.z), qf14 = bf_lo(qc.w), qf15 = bf_hi(qc.w);
#endif

    float ssum = 0.0f;
    float acc[8] = {0.f, 0.f, 0.f, 0.f, 0.f, 0.f, 0.f, 0.f};
    for (int base = 0; base < deg; base += 16) {
        int el0 = base + hd;
        int el1 = el0 + 8;
        unsigned int pk0 = esort[start + ((el0 < deg) ? el0 : 0)];
        unsigned int pk1 = esort[start + ((el1 < deg) ? el1 : 0)];
        unsigned int src0 = pk0 & 0xFFFF, etv0 = (pk0 >> 16) & 0x3F;
        unsigned int src1 = pk1 & 0xFFFF, etv1 = (pk1 >> 16) & 0x3F;
        const uint4* kp0 = (const uint4*)(kvu + (src0 << 7) + h * 8);
        const uint4* rp0 = (const uint4*)(relu + (etv0 << 6) + h * 8);
        const uint4* kp1 = (const uint4*)(kvu + (src1 << 7) + h * 8);
        const uint4* rp1 = (const uint4*)(relu + (etv1 << 6) + h * 8);
        uint4 ka0 = kp0[0], kb0 = kp0[1];
        uint4 ra0 = rp0[0], rb0 = rp0[1];
        uint4 ka1 = kp1[0], kb1 = kp1[1];
        uint4 ra1 = rp1[0], rb1 = rp1[1];
        float s0, s1;
#if HAVE_DOT2
        {
            float a0 = dot2acc(qa.x, ka0.x, 0.0f), a1 = dot2acc(qa.y, ka0.y, 0.0f);
            float a2 = dot2acc(qa.z, ka0.z, 0.0f), a3 = dot2acc(qa.w, ka0.w, 0.0f);
            a0 = dot2acc(qc.x, kb0.x, a0); a1 = dot2acc(qc.y, kb0.y, a1);
            a2 = dot2acc(qc.z, kb0.z, a2); a3 = dot2acc(qc.w, kb0.w, a3);
            a0 = dot2acc(qa.x, ra0.x, a0); a1 = dot2acc(qa.y, ra0.y, a1);
            a2 = dot2acc(qa.z, ra0.z, a2); a3 = dot2acc(qa.w, ra0.w, a3);
            a0 = dot2acc(qc.x, rb0.x, a0); a1 = dot2acc(qc.y, rb0.y, a1);
            a2 = dot2acc(qc.z, rb0.z, a2); a3 = dot2acc(qc.w, rb0.w, a3);
            s0 = (a0 + a1) + (a2 + a3);
        }
        {
            float a0 = dot2acc(qa.x, ka1.x, 0.0f), a1 = dot2acc(qa.y, ka1.y, 0.0f);
            float a2 = dot2acc(qa.z, ka1.z, 0.0f), a3 = dot2acc(qa.w, ka1.w, 0.0f);
            a0 = dot2acc(qc.x, kb1.x, a0); a1 = dot2acc(qc.y, kb1.y, a1);
            a2 = dot2acc(qc.z, kb1.z, a2); a3 = dot2acc(qc.w, kb1.w, a3);
            a0 = dot2acc(qa.x, ra1.x, a0); a1 = dot2acc(qa.y, ra1.y, a1);
            a2 = dot2acc(qa.z, ra1.z, a2); a3 = dot2acc(qa.w, ra1.w, a3);
            a0 = dot2acc(qc.x, rb1.x, a0); a1 = dot2acc(qc.y, rb1.y, a1);
            a2 = dot2acc(qc.z, rb1.z, a2); a3 = dot2acc(qc.w, rb1.w, a3);
            s1 = (a0 + a1) + (a2 + a3);
        }
#else
        {
            float a0 = qf0 * (bf_lo(ka0.x) + bf_lo(ra0.x)) + qf4 * (bf_lo(ka0.z) + bf_lo(ra0.z))
                     + qf8 * (bf_lo(kb0.x) + bf_lo(rb0.x)) + qf12 * (bf_lo(kb0.z) + bf_lo(rb0.z));
            float a1 = qf1 * (bf_hi(ka0.x) + bf_hi(ra0.x)) + qf5 * (bf_hi(ka0.z) + bf_hi(ra0.z))
                     + qf9 * (bf_hi(kb0.x) + bf_hi(rb0.x)) + qf13 * (bf_hi(kb0.z) + bf_hi(rb0.z));
            float a2 = qf2 * (bf_lo(ka0.y) + bf_lo(ra0.y)) + qf6 * (bf_lo(ka0.w) + bf_lo(ra0.w))
                     + qf10 * (bf_lo(kb0.y) + bf_lo(rb0.y)) + qf14 * (bf_lo(kb0.w) + bf_lo(rb0.w));
            float a3 = qf3 * (bf_hi(ka0.y) + bf_hi(ra0.y)) + qf7 * (bf_hi(ka0.w) + bf_hi(ra0.w))
                     + qf11 * (bf_hi(kb0.y) + bf_hi(rb0.y)) + qf15 * (bf_hi(kb0.w) + bf_hi(rb0.w));
            s0 = (a0 + a1) + (a2 + a3);
        }
        {
            float a0 = qf0 * (bf_lo(ka1.x) + bf_lo(ra1.x)) + qf4 * (bf_lo(ka1.z) + bf_lo(ra1.z))
                     + qf8 * (bf_lo(kb1.x) + bf_lo(rb1.x)) + qf12 * (bf_lo(kb1.z) + bf_lo(rb1.z));
            float a1 = qf1 * (bf_hi(ka1.x) + bf_hi(ra1.x)) + qf5 * (bf_hi(ka1.z) + bf_hi(ra1.z))
                     + qf9 * (bf_hi(kb1.x) + bf_hi(rb1.x)) + qf13 * (bf_hi(kb1.z) + bf_hi(rb1.z));
            float a2 = qf2 * (bf_lo(ka1.y) + bf_lo(ra1.y)) + qf6 * (bf_lo(ka1.w) + bf_lo(ra1.w))
                     + qf10 * (bf_lo(kb1.y) + bf_lo(rb1.y)) + qf14 * (bf_lo(kb1.w) + bf_lo(rb1.w));
            float a3 = qf3 * (bf_hi(ka1.y) + bf_hi(ra1.y)) + qf7 * (bf_hi(ka1.w) + bf_hi(ra1.w))
                     + qf11 * (bf_hi(kb1.y) + bf_hi(rb1.y)) + qf15 * (bf_hi(kb1.w) + bf_hi(rb1.w));
            s1 = (a0 + a1) + (a2 + a3);
        }
#endif
        unsigned int wb0 = (el0 < deg) ? (unsigned int)f2bf(__expf(s0 * 0.25f)) : 0u;
        unsigned int wb1 = (el1 < deg) ? (unsigned int)f2bf(__expf(s1 * 0.25f)) : 0u;
        ssum += __uint_as_float(wb0 << 16) + __uint_as_float(wb1 << 16);
        unsigned int pw0 = (wb0 << 16) | src0;
        unsigned int pw1 = (wb1 << 16) | src1;
        #pragma unroll
        for (int t = 0; t < 4; ++t) {
            unsigned int pj = (t < 2) ? __shfl(pw0, (t * 4 + quarter) * 8 + (qi >> 1))
                                      : __shfl(pw1, ((t - 2) * 4 + quarter) * 8 + (qi >> 1));
            float wj = bf_hi(pj);
            unsigned int sj = pj & 0xFFFFu;
            uint4 v = *(const uint4*)(kvu + (sj << 7) + 64 + qi * 4);
            acc[0] += wj * bf_lo(v.x); acc[1] += wj * bf_hi(v.x);
            acc[2] += wj * bf_lo(v.y); acc[3] += wj * bf_hi(v.y);
            acc[4] += wj * bf_lo(v.z); acc[5] += wj * bf_hi(v.z);
            acc[6] += wj * bf_lo(v.w); acc[7] += wj * bf_hi(v.w);
        }
    }
    #pragma unroll
    for (int off = 8; off < 64; off <<= 1) ssum += __shfl_xor(ssum, off);
    #pragma unroll
    for (int k = 0; k < 8; ++k) {
        acc[k] += __shfl_xor(acc[k], 16);
        acc[k] += __shfl_xor(acc[k], 32);
    }
    float inv = 1.0f / (__shfl(ssum, qi >> 1) + 1e-8f);
    if (lane < 16) {
        uint4 o;
        o.x = pack_bf2(acc[0] * inv, acc[1] * inv);
        o.y = pack_bf2(acc[2] * inv, acc[3] * inv);
        o.z = pack_bf2(acc[4] * inv, acc[5] * inv);
        o.w = pack_bf2(acc[6] * inv, acc[7] * inv);
        *(uint4*)(abuf + (unsigned)node * 64 + qi * 4) = o;
    }
}

// ---- out = Abf16 @ Wo + bo via MFMA; fp32 LDS-staged epilogue for full-sector streaming stores ----
__global__ __launch_bounds__(256) void out_mfma_kernel(
    const unsigned short* __restrict__ abuf, const unsigned short* __restrict__ Wot,
    const float* __restrict__ bo, float* __restrict__ out) {
    int row0 = blockIdx.x * 64;
    int wave = threadIdx.x >> 6;
    int lane = threadIdx.x & 63;
    int col  = lane & 15;
    int quad = lane >> 4;
    __shared__ float otile[64][132];   // fp32 C tile, 528B rows (16B-aligned)

    short8 afr[4][4];
    #pragma unroll
    for (int t = 0; t < 4; ++t) {
        int arow = row0 + t * 16 + col;
        int asafe = (arow < N_NODES) ? arow : (N_NODES - 1);
        #pragma unroll
        for (int kk = 0; kk < 4; ++kk)
            afr[t][kk] = *(const short8*)(abuf + (size_t)asafe * HID + kk * 32 + quad * 8);
    }

    #pragma unroll
    for (int nn = 0; nn < 2; ++nn) {
        int n = wave * 2 + nn;
        float b = bo[n * 16 + col];
        floatx4 acc[4];
        #pragma unroll
        for (int t = 0; t < 4; ++t) acc[t] = (floatx4){b, b, b, b};
        short8 bfr[4];
        #pragma unroll
        for (int kk = 0; kk < 4; ++kk)
            bfr[kk] = *(const short8*)(Wot + (size_t)(n * 16 + col) * HID + kk * 32 + quad * 8);
        #pragma unroll
        for (int kk = 0; kk < 4; ++kk)
            #pragma unroll
            for (int t = 0; t < 4; ++t)
                acc[t] = __builtin_amdgcn_mfma_f32_16x16x32_bf16(afr[t][kk], bfr[kk], acc[t], 0, 0, 0);
        #pragma unroll
        for (int t = 0; t < 4; ++t)
            #pragma unroll
            for (int i = 0; i < 4; ++i)
                otile[t * 16 + quad * 4 + i][n * 16 + col] = acc[t][i];
    }
    __syncthreads();
    // coalesced copy-out: 2048 chunks of 16B (64 rows x 512B), 8 per thread
    #pragma unroll
    for (int k = 0; k < 8; ++k) {
        int chunk = threadIdx.x + k * 256;
        int r = chunk >> 5, c = chunk & 31;
        int row = row0 + r;
        if (row < N_NODES) {
            float4 v = *(const float4*)&otile[r][c * 4];
            *(float4*)(out + (size_t)row * HID + c * 4) = v;
        }
    }
}

extern "C" void kernel_launch(void* const* d_in, const int* in_sizes, int n_in,
                              void* d_out, int out_size, void* d_ws, size_t ws_size,
                              hipStream_t stream) {
    const float* nf    = (const float*)d_in[0];
    const float* query = (const float*)d_in[1];
    const float* rel   = (const float*)d_in[2];
    const float* Wq    = (const float*)d_in[3];
    const float* bq    = (const float*)d_in[4];
    const float* Wk    = (const float*)d_in[5];
    const float* bk    = (const float*)d_in[6];
    const float* Wv    = (const float*)d_in[7];
    const float* bv    = (const float*)d_in[8];
    const float* Wo    = (const float*)d_in[9];
    const float* bo    = (const float*)d_in[10];
    const int*   ei    = (const int*)d_in[11];
    const int*   et    = (const int*)d_in[12];
    float* out = (float*)d_out;

    char* ws = (char*)d_ws;
    unsigned short* qb16 = (unsigned short*)ws; ws += (size_t)N_NODES * HID * 2;
    unsigned short* kv16 = (unsigned short*)ws; ws += (size_t)N_NODES * 256 * 2;
    unsigned int* abuf   = (unsigned int*)ws;   ws += (size_t)N_NODES * 64 * 4;
    float* bqe           = (float*)ws;          ws += 128 * 4;
    float* bke           = (float*)ws;          ws += 128 * 4;
    unsigned short* Wt   = (unsigned short*)ws; ws += (size_t)4 * HID * HID * 2;
    unsigned short* relbf = (unsigned short*)ws; ws += (size_t)64 * HID * 2;
    unsigned short* nfb  = (unsigned short*)ws; ws += (size_t)N_NODES * HID * 2;
    unsigned int* recs   = (unsigned int*)ws;   ws += (size_t)NBIN * CAPB * 4;
    unsigned int* esort  = (unsigned int*)ws;   ws += (size_t)NBIN * CAPB * 4;
    unsigned int* nodeinfo = (unsigned int*)ws; ws += (size_t)N_NODES * 4;
    int* cursor          = (int*)ws;            ws += (size_t)NBIN * 4;

    hipMemsetAsync(cursor, 0, (size_t)NBIN * 4, stream);
    prep_kernel<<<K2_BLOCKS + NFB_BLOCKS + 258, 256, 0, stream>>>(
        nf, query, rel, Wq, bq, Wk, bk, Wv, Wo, ei, et,
        cursor, recs, Wt, relbf, bqe, bke, nfb);
    qkv_kernel<<<NBIN + QKV_BLOCKS, 256, 0, stream>>>(
        nfb, Wt, bqe, bke, bv, cursor, recs, esort, nodeinfo, qb16, kv16);
    attn_kernel<<<N_NODES / 4, 256, 0, stream>>>(
        (const unsigned int*)qb16, (const unsigned int*)kv16,
        (const unsigned int*)relbf, nodeinfo, esort, abuf);
    out_mfma_kernel<<<QKV_BLOCKS, 256, 0, stream>>>(
        (const unsigned short*)abuf, Wt + (size_t)3 * HID * HID, bo, out);
}